// Round 1
// baseline (78.257 us; speedup 1.0000x reference)
//
#include <hip/hip_runtime.h>
#include <math.h>

#define STRIDE_F 8.0f
#define N_CLS 80
#define NA 3
#define NCH (5 + N_CLS)   // 85
#define NG 64
#define NGT 50
#define NANCH 9
#define IGNORE_THRE 0.6f
#define EPS_T 1e-8f

__device__ __forceinline__ float bce_logits(float x, float t) {
    return fmaxf(x, 0.0f) - x * t + log1pf(expf(-fabsf(x)));
}

// Per-GT precompute: anchor argmax, validity, target cell, target ltrb logs, weight.
// One block per batch, 64 threads (g = thread).
__global__ void fcos_gt_prep(const float* __restrict__ labels,
                             const float* __restrict__ all_anchors,
                             const int* __restrict__ anchor_indices,
                             const int* __restrict__ img_size,
                             float* __restrict__ gtbuf,
                             int* __restrict__ anyv) {
    int b = blockIdx.x;
    int g = threadIdx.x;
    __shared__ int s_any;
    if (g == 0) s_any = 0;
    __syncthreads();
    if (g < NGT) {
        const float* lab = labels + (b * NGT + g) * 5;
        float cls = lab[0];
        float gx = lab[1], gy = lab[2], gw = lab[3], gh = lab[4];

        // argmax IoU(wh) over all 9 anchors, first-max tie-break
        int best = 0; float bi = -1.0f;
        for (int k = 0; k < NANCH; ++k) {
            float aw = all_anchors[2 * k], ah = all_anchors[2 * k + 1];
            float inter = fminf(gw, aw) * fminf(gh, ah);
            float iou = inter / (gw * gh + aw * ah - inter);
            if (iou > bi) { bi = iou; best = k; }
        }
        int bn = best % NA;
        int valid = 0;
        for (int j = 0; j < NA; ++j) if (anchor_indices[j] == best) valid = 1;

        int ai = anchor_indices[bn];
        float aw = all_anchors[2 * ai], ah = all_anchors[2 * ai + 1];

        float ccx = (floorf(gx / STRIDE_F) + 0.5f) * STRIDE_F;
        float ccy = (floorf(gy / STRIDE_F) + 0.5f) * STRIDE_F;
        float l   = fmaxf(ccx - (gx - gw * 0.5f), 0.0f);
        float t   = fmaxf(ccy - (gy - gh * 0.5f), 0.0f);
        float r   = fmaxf(gx + gw * 0.5f - ccx, 0.0f);
        float btm = fmaxf(gy + gh * 0.5f - ccy, 0.0f);
        float fimg = (float)(*img_size);

        float* o = gtbuf + (b * NGT + g) * 16;
        o[0] = gx; o[1] = gy; o[2] = gw; o[3] = gh;
        o[4] = (float)valid;
        o[5] = (float)bn;
        o[6] = (float)((int)(gx / STRIDE_F));   // ti
        o[7] = (float)((int)(gy / STRIDE_F));   // tj
        o[8]  = logf(l   / aw + EPS_T);
        o[9]  = logf(t   / ah + EPS_T);
        o[10] = logf(r   / aw + EPS_T);
        o[11] = logf(btm / ah + EPS_T);
        o[12] = 2.0f - gw * gh / fimg / fimg;   // wvec
        o[13] = cls;
        o[14] = 0.0f; o[15] = 0.0f;
        if (valid) atomicOr(&s_any, 1);
    }
    __syncthreads();
    if (g == 0) anyv[b] = s_any;
}

// Main: one thread per (a, y, x) cell; blockIdx.y = batch.
__global__ __launch_bounds__(256) void fcos_main(const float* __restrict__ raw,
                          const float* __restrict__ all_anchors,
                          const int* __restrict__ anchor_indices,
                          const int* __restrict__ img_size,
                          const float* __restrict__ gtbuf,
                          const int* __restrict__ anyv,
                          float* __restrict__ out) {
    __shared__ float sgt[NGT * 16];
    int b = blockIdx.y;
    int tid = threadIdx.x;
    for (int i = tid; i < NGT * 16; i += 256) sgt[i] = gtbuf[b * NGT * 16 + i];
    __syncthreads();

    int c = blockIdx.x * 256 + tid;   // 0 .. 12287 (exact: 48 blocks * 256)
    int a = c >> 12;
    int y = (c >> 6) & (NG - 1);
    int x = c & (NG - 1);

    float fimg = (float)(*img_size);
    int ai = anchor_indices[a];
    float aw = all_anchors[2 * ai], ah = all_anchors[2 * ai + 1];

    const float* rb = raw + ((size_t)(b * (NA * NCH) + a * NCH) << 12) + (y << 6) + x;
    float r0 = rb[0];
    float r1 = rb[1 * 4096];
    float r2 = rb[2 * 4096];
    float r3 = rb[3 * 4096];
    float r4 = rb[4 * 4096];

    // ltrb = clip(exp(raw)*scale, 0, img); exp>=0 so only upper clip matters
    float lp = fminf(expf(r0) * aw, fimg);
    float tp = fminf(expf(r1) * ah, fimg);
    float rp = fminf(expf(r2) * aw, fimg);
    float bp = fminf(expf(r3) * ah, fimg);

    float px = ((float)x + 0.5f) * STRIDE_F + (rp - lp) * 0.5f;
    float py = ((float)y + 0.5f) * STRIDE_F + (bp - tp) * 0.5f;
    float pw = lp + rp;
    float ph = tp + bp;
    float areap = pw * ph;
    float pxl = px - pw * 0.5f, pxr = px + pw * 0.5f;
    float pyt = py - ph * 0.5f, pyb = py + ph * 0.5f;

    float maxiou = 0.0f;
    int win = -1;
    #pragma unroll 5
    for (int g = 0; g < NGT; ++g) {
        const float* s = sgt + g * 16;
        float gx = s[0], gy = s[1], gw = s[2], gh = s[3];
        float tlx = fmaxf(pxl, gx - gw * 0.5f);
        float tly = fmaxf(pyt, gy - gh * 0.5f);
        float brx = fminf(pxr, gx + gw * 0.5f);
        float bry = fminf(pyb, gy + gh * 0.5f);
        float inter = fmaxf(brx - tlx, 0.0f) * fmaxf(bry - tly, 0.0f);
        float iou = inter / (areap + gw * gh - inter + 1e-12f);
        maxiou = fmaxf(maxiou, iou);
        // last valid GT mapping to this exact cell wins (matches JAX scatter order)
        if (s[4] != 0.0f && (int)s[5] == a && (int)s[6] == x && (int)s[7] == y) win = g;
    }

    bool cmask = anyv[b] ? (maxiou < IGNORE_THRE) : true;
    float loss = 0.0f;
    if (win >= 0) {
        loss += bce_logits(r4, 1.0f);   // conf_mask forced true at GT cells
        const float* s = sgt + win * 16;
        float w = s[12];
        float d0 = r0 - s[8], d1 = r1 - s[9], d2 = r2 - s[10], d3 = r3 - s[11];
        loss += 0.5f * w * (d0 * d0 + d1 * d1 + d2 * d2 + d3 * d3);
        int cls = (int)s[13];
        for (int cc = 0; cc < N_CLS; ++cc) {
            float xr = rb[(size_t)(5 + cc) * 4096];
            loss += bce_logits(xr, (cc == cls) ? 1.0f : 0.0f);
        }
    } else if (cmask) {
        loss += bce_logits(r4, 0.0f);
    }

    // block reduction: wave64 shuffle, then LDS across 4 waves
    for (int off = 32; off > 0; off >>= 1)
        loss += __shfl_down(loss, off, 64);
    __shared__ float swave[4];
    int lane = tid & 63, wid = tid >> 6;
    if (lane == 0) swave[wid] = loss;
    __syncthreads();
    if (tid == 0) {
        float s = swave[0] + swave[1] + swave[2] + swave[3];
        atomicAdd(out, s);
    }
}

extern "C" void kernel_launch(void* const* d_in, const int* in_sizes, int n_in,
                              void* d_out, int out_size, void* d_ws, size_t ws_size,
                              hipStream_t stream) {
    const float* raw            = (const float*)d_in[0];
    const float* labels         = (const float*)d_in[1];
    const float* all_anchors    = (const float*)d_in[2];
    const int*   anchor_indices = (const int*)d_in[3];
    const int*   img_size       = (const int*)d_in[4];
    float* out = (float*)d_out;

    int nB = in_sizes[0] / (NA * NCH * NG * NG);   // 16

    float* gtbuf = (float*)d_ws;
    int*   anyv  = (int*)((char*)d_ws + (size_t)nB * NGT * 16 * sizeof(float));

    hipMemsetAsync(d_out, 0, sizeof(float), stream);
    fcos_gt_prep<<<nB, 64, 0, stream>>>(labels, all_anchors, anchor_indices,
                                        img_size, gtbuf, anyv);
    fcos_main<<<dim3(48, nB), 256, 0, stream>>>(raw, all_anchors, anchor_indices,
                                                img_size, gtbuf, anyv, out);
}

// Round 2
// 31.484 us; speedup vs baseline: 2.4856x; 2.4856x over previous
//
#include <hip/hip_runtime.h>
#include <math.h>

#define STRIDE_F 8.0f
#define N_CLS 80
#define NA 3
#define NCH (5 + N_CLS)   // 85
#define NG 64
#define NGT 50
#define NANCH 9
#define EPS_T 1e-8f

__device__ __forceinline__ float bce_logits(float x, float t) {
    return fmaxf(x, 0.0f) - x * t + log1pf(expf(-fabsf(x)));
}

// ---------------------------------------------------------------------------
// Per-GT precompute. One block per batch, 64 threads (1 wave), g = thread.
// gtbuf layout per GT (stride 16 floats):
//  [0..3]  gxl, gyt, gxr, gyb      (corner box)
//  [4]     0.375f * areaG          (for divide-free ignore test)
//  [5]     key bits (int): valid ? (bn<<12)|(tj<<6)|ti : -1
//  [8..11] target ltrb logs
//  [12]    wvec
//  [13]    cls
//  [14]    winner&&valid flag (1.0/0.0)  — for the cls kernel
// ---------------------------------------------------------------------------
__global__ __launch_bounds__(64) void fcos_gt_prep(
        const float* __restrict__ labels,
        const float* __restrict__ all_anchors,
        const int* __restrict__ anchor_indices,
        const int* __restrict__ img_size,
        float* __restrict__ gtbuf,
        int* __restrict__ anyv) {
    int b = blockIdx.x;
    int g = threadIdx.x;
    __shared__ int s_key[64];

    s_key[g] = -2 - g;             // unique non-matching default
    int key = -1;
    int valid = 0;
    float gx = 0, gy = 0, gw = 0, gh = 0, cls = 0;

    if (g < NGT) {
        const float* lab = labels + (b * NGT + g) * 5;
        cls = lab[0];
        gx = lab[1]; gy = lab[2]; gw = lab[3]; gh = lab[4];

        // argmax IoU(wh) over all 9 anchors, first-max tie-break
        int best = 0; float bi = -1.0f;
        for (int k = 0; k < NANCH; ++k) {
            float aw = all_anchors[2 * k], ah = all_anchors[2 * k + 1];
            float inter = fminf(gw, aw) * fminf(gh, ah);
            float iou = inter / (gw * gh + aw * ah - inter);
            if (iou > bi) { bi = iou; best = k; }
        }
        int bn = best % NA;
        for (int j = 0; j < NA; ++j) if (anchor_indices[j] == best) valid = 1;

        int ti = (int)(gx / STRIDE_F);
        int tj = (int)(gy / STRIDE_F);
        key = valid ? ((bn << 12) | (tj << 6) | ti) : -1;
        s_key[g] = key;
    }
    __syncthreads();

    if (g < NGT) {
        // winner = no later GT writes the same cell (JAX scatter: last wins)
        int winner = 1;
        for (int gp = g + 1; gp < NGT; ++gp)
            if (s_key[gp] == key) winner = 0;

        int ai = anchor_indices[(key >= 0) ? (key >> 12) : 0];
        // (bn only meaningful when valid; fine either way)
        int bn = 0;
        {   // recompute bn for anchor lookup (valid or not, harmless)
            int best = 0; float bi = -1.0f;
            for (int k = 0; k < NANCH; ++k) {
                float aw = all_anchors[2 * k], ah = all_anchors[2 * k + 1];
                float inter = fminf(gw, aw) * fminf(gh, ah);
                float iou = inter / (gw * gh + aw * ah - inter);
                if (iou > bi) { bi = iou; best = k; }
            }
            bn = best % NA;
        }
        ai = anchor_indices[bn];
        float aw = all_anchors[2 * ai], ah = all_anchors[2 * ai + 1];

        float ccx = (floorf(gx / STRIDE_F) + 0.5f) * STRIDE_F;
        float ccy = (floorf(gy / STRIDE_F) + 0.5f) * STRIDE_F;
        float l   = fmaxf(ccx - (gx - gw * 0.5f), 0.0f);
        float t   = fmaxf(ccy - (gy - gh * 0.5f), 0.0f);
        float r   = fmaxf(gx + gw * 0.5f - ccx, 0.0f);
        float btm = fmaxf(gy + gh * 0.5f - ccy, 0.0f);
        float fimg = (float)(*img_size);

        float* o = gtbuf + (b * NGT + g) * 16;
        o[0] = gx - gw * 0.5f;
        o[1] = gy - gh * 0.5f;
        o[2] = gx + gw * 0.5f;
        o[3] = gy + gh * 0.5f;
        o[4] = 0.375f * (gw * gh);
        o[5] = __int_as_float(key);
        o[6] = 0.0f; o[7] = 0.0f;
        o[8]  = logf(l   / aw + EPS_T);
        o[9]  = logf(t   / ah + EPS_T);
        o[10] = logf(r   / aw + EPS_T);
        o[11] = logf(btm / ah + EPS_T);
        o[12] = 2.0f - gw * gh / fimg / fimg;
        o[13] = cls;
        o[14] = (winner && valid) ? 1.0f : 0.0f;
        o[15] = 0.0f;
    }

    unsigned long long m = __ballot(valid);
    if (g == 0) anyv[b] = (m != 0ULL) ? 1 : 0;
}

// ---------------------------------------------------------------------------
// Main: conf BCE everywhere + bbox/conf at GT cells. One thread per (a,y,x).
// blockIdx.y = batch. Divide-free ignore test; win via key == flat cell id.
// ---------------------------------------------------------------------------
__global__ __launch_bounds__(256) void fcos_main(
        const float* __restrict__ raw,
        const float* __restrict__ all_anchors,
        const int* __restrict__ anchor_indices,
        const int* __restrict__ img_size,
        const float* __restrict__ gtbuf,
        const int* __restrict__ anyv,
        float* __restrict__ out) {
    __shared__ float sgt[NGT * 16];
    int b = blockIdx.y;
    int tid = threadIdx.x;
    for (int i = tid; i < NGT * 16; i += 256) sgt[i] = gtbuf[b * NGT * 16 + i];
    __syncthreads();

    int c = blockIdx.x * 256 + tid;   // flat cell id == (a<<12)|(y<<6)|x
    int a = c >> 12;
    int y = (c >> 6) & (NG - 1);
    int x = c & (NG - 1);

    float fimg = (float)(*img_size);
    int ai = anchor_indices[a];
    float aw = all_anchors[2 * ai], ah = all_anchors[2 * ai + 1];

    const float* rb = raw + ((size_t)(b * (NA * NCH) + a * NCH) << 12) + (y << 6) + x;
    float r0 = rb[0];
    float r1 = rb[1 * 4096];
    float r2 = rb[2 * 4096];
    float r3 = rb[3 * 4096];
    float r4 = rb[4 * 4096];

    float lp = fminf(expf(r0) * aw, fimg);
    float tp = fminf(expf(r1) * ah, fimg);
    float rp = fminf(expf(r2) * aw, fimg);
    float bp = fminf(expf(r3) * ah, fimg);

    float px = ((float)x + 0.5f) * STRIDE_F + (rp - lp) * 0.5f;
    float py = ((float)y + 0.5f) * STRIDE_F + (bp - tp) * 0.5f;
    float pw = lp + rp;
    float ph = tp + bp;
    float base = 0.375f * (pw * ph + 1e-12f);   // 0.375*(areaP + eps)
    float pxl = px - pw * 0.5f, pxr = px + pw * 0.5f;
    float pyt = py - ph * 0.5f, pyb = py + ph * 0.5f;

    // iou >= 0.6  <=>  inter >= 0.375*(areaP + areaG + 1e-12)
    float maxdiff = -1.0f;   // max over g of (inter - threshold)
    int win = -1;
    #pragma unroll 10
    for (int g = 0; g < NGT; ++g) {
        const float* s = sgt + g * 16;
        float tlx = fmaxf(pxl, s[0]);
        float tly = fmaxf(pyt, s[1]);
        float brx = fminf(pxr, s[2]);
        float bry = fminf(pyb, s[3]);
        float inter = fmaxf(brx - tlx, 0.0f) * fmaxf(bry - tly, 0.0f);
        float thr = base + s[4];
        maxdiff = fmaxf(maxdiff, inter - thr);
        int key = __float_as_int(s[5]);
        if (key == c) win = g;     // ascending g: last match wins
    }

    bool cmask = anyv[b] ? (maxdiff < 0.0f) : true;
    float loss = 0.0f;
    if (win >= 0) {
        loss += bce_logits(r4, 1.0f);   // conf_mask forced true at GT cells
        const float* s = sgt + win * 16;
        float w = s[12];
        float d0 = r0 - s[8], d1 = r1 - s[9], d2 = r2 - s[10], d3 = r3 - s[11];
        loss += 0.5f * w * (d0 * d0 + d1 * d1 + d2 * d2 + d3 * d3);
    } else if (cmask) {
        loss += bce_logits(r4, 0.0f);
    }

    for (int off = 32; off > 0; off >>= 1)
        loss += __shfl_down(loss, off, 64);
    __shared__ float swave[4];
    int lane = tid & 63, wid = tid >> 6;
    if (lane == 0) swave[wid] = loss;
    __syncthreads();
    if (tid == 0) {
        float s = swave[0] + swave[1] + swave[2] + swave[3];
        atomicAdd(out, s);
    }
}

// ---------------------------------------------------------------------------
// Class loss: one 64-lane wave per GT; lanes gather the 80 class channels in
// parallel (lane t handles cc=t and cc=t+64). grid = (NGT, nB).
// ---------------------------------------------------------------------------
__global__ __launch_bounds__(64) void fcos_cls(
        const float* __restrict__ raw,
        const float* __restrict__ gtbuf,
        float* __restrict__ out) {
    int b = blockIdx.y;
    int g = blockIdx.x;
    int t = threadIdx.x;

    const float* s = gtbuf + (b * NGT + g) * 16;
    if (s[14] == 0.0f) return;      // not a winning valid GT

    int key = __float_as_int(s[5]);
    int bn = key >> 12;
    int tj = (key >> 6) & (NG - 1);
    int ti = key & (NG - 1);
    int cls = (int)s[13];

    const float* rb = raw + ((size_t)(b * (NA * NCH) + bn * NCH + 5) << 12)
                          + (tj << 6) + ti;
    float loss = 0.0f;
    {
        float xr = rb[(size_t)t * 4096];
        loss += bce_logits(xr, (t == cls) ? 1.0f : 0.0f);
    }
    if (t < N_CLS - 64) {
        int cc = t + 64;
        float xr = rb[(size_t)cc * 4096];
        loss += bce_logits(xr, (cc == cls) ? 1.0f : 0.0f);
    }
    for (int off = 32; off > 0; off >>= 1)
        loss += __shfl_down(loss, off, 64);
    if (t == 0) atomicAdd(out, loss);
}

extern "C" void kernel_launch(void* const* d_in, const int* in_sizes, int n_in,
                              void* d_out, int out_size, void* d_ws, size_t ws_size,
                              hipStream_t stream) {
    const float* raw            = (const float*)d_in[0];
    const float* labels         = (const float*)d_in[1];
    const float* all_anchors    = (const float*)d_in[2];
    const int*   anchor_indices = (const int*)d_in[3];
    const int*   img_size       = (const int*)d_in[4];
    float* out = (float*)d_out;

    int nB = in_sizes[0] / (NA * NCH * NG * NG);   // 16

    float* gtbuf = (float*)d_ws;
    int*   anyv  = (int*)((char*)d_ws + (size_t)nB * NGT * 16 * sizeof(float));

    hipMemsetAsync(d_out, 0, sizeof(float), stream);
    fcos_gt_prep<<<nB, 64, 0, stream>>>(labels, all_anchors, anchor_indices,
                                        img_size, gtbuf, anyv);
    fcos_main<<<dim3(48, nB), 256, 0, stream>>>(raw, all_anchors, anchor_indices,
                                                img_size, gtbuf, anyv, out);
    fcos_cls<<<dim3(NGT, nB), 64, 0, stream>>>(raw, gtbuf, out);
}

// Round 3
// 26.296 us; speedup vs baseline: 2.9760x; 1.1973x over previous
//
#include <hip/hip_runtime.h>
#include <math.h>

#define STRIDE_F 8.0f
#define N_CLS 80
#define NA 3
#define NCH (5 + N_CLS)   // 85
#define NG 64
#define NGT 50
#define NANCH 9
#define EPS_T 1e-8f
#define MAIN_BLOCKS 48            // 48*256 = NA*NG*NG cells
#define CLS_BLOCKS 13             // ceil(NGT/4), 4 GT-waves per block

__device__ __forceinline__ float bce_logits(float x, float t) {
    return fmaxf(x, 0.0f) - x * t + log1pf(expf(-fabsf(x)));
}

// One fused kernel. grid = (MAIN_BLOCKS + CLS_BLOCKS, nB).
// Every block redundantly computes the per-GT prep for its batch into LDS
// (cheap: 50 GTs x (9-anchor argmax + 4 logf)), then either:
//   bx < 48  : per-cell conf/bbox loss (1 thread = 1 (a,y,x) cell)
//   bx >= 48 : class loss, one 64-lane wave per winning GT (parallel gather
//              of the 80 class channels)
__global__ __launch_bounds__(256) void fcos_fused(
        const float* __restrict__ raw,
        const float* __restrict__ labels,
        const float* __restrict__ all_anchors,
        const int* __restrict__ anchor_indices,
        const int* __restrict__ img_size,
        float* __restrict__ out) {
    __shared__ float4 s_box[NGT];   // corner box (xl,yt,xr,yb)
    __shared__ float4 s_tl[NGT];    // target ltrb logs
    __shared__ float  s_thr[NGT];   // 0.375 * areaG
    __shared__ int    s_key[NGT];   // valid ? (bn<<12)|(tj<<6)|ti : -1
    __shared__ float  s_wv[NGT];    // wvec
    __shared__ int    s_cls[NGT];
    __shared__ int    s_win[NGT];   // winner && valid
    __shared__ int    s_any;
    __shared__ float  swave[4];

    int b = blockIdx.y;
    int tid = threadIdx.x;
    float fimg = (float)(*img_size);

    // ---------------- per-block GT prep (threads 0..49, wave 0) -------------
    int valid = 0, key = -1, bn = 0;
    float gx = 0, gy = 0, gw = 0, gh = 0, cls = 0;
    if (tid < NGT) {
        const float* lab = labels + (b * NGT + tid) * 5;
        cls = lab[0];
        gx = lab[1]; gy = lab[2]; gw = lab[3]; gh = lab[4];
        int best = 0; float bi = -1.0f;
        for (int k = 0; k < NANCH; ++k) {
            float aw = all_anchors[2 * k], ah = all_anchors[2 * k + 1];
            float inter = fminf(gw, aw) * fminf(gh, ah);
            float iou = inter / (gw * gh + aw * ah - inter);
            if (iou > bi) { bi = iou; best = k; }
        }
        bn = best % NA;
        for (int j = 0; j < NA; ++j) if (anchor_indices[j] == best) valid = 1;
        int ti = (int)(gx / STRIDE_F);
        int tj = (int)(gy / STRIDE_F);
        key = valid ? ((bn << 12) | (tj << 6) | ti) : -1;
        s_key[tid] = key;
    }
    __syncthreads();
    if (tid < NGT) {
        // JAX scatter "last valid update wins": winner iff no later GT
        // targets the same cell
        int winner = valid;
        for (int gp = tid + 1; gp < NGT; ++gp)
            if (s_key[gp] == key) winner = 0;

        int ai = anchor_indices[bn];
        float aw = all_anchors[2 * ai], ah = all_anchors[2 * ai + 1];
        float ccx = (floorf(gx / STRIDE_F) + 0.5f) * STRIDE_F;
        float ccy = (floorf(gy / STRIDE_F) + 0.5f) * STRIDE_F;
        float l   = fmaxf(ccx - (gx - gw * 0.5f), 0.0f);
        float t   = fmaxf(ccy - (gy - gh * 0.5f), 0.0f);
        float r   = fmaxf(gx + gw * 0.5f - ccx, 0.0f);
        float btm = fmaxf(gy + gh * 0.5f - ccy, 0.0f);

        s_box[tid] = make_float4(gx - gw * 0.5f, gy - gh * 0.5f,
                                 gx + gw * 0.5f, gy + gh * 0.5f);
        s_thr[tid] = 0.375f * (gw * gh);
        s_tl[tid]  = make_float4(logf(l / aw + EPS_T), logf(t / ah + EPS_T),
                                 logf(r / aw + EPS_T), logf(btm / ah + EPS_T));
        s_wv[tid]  = 2.0f - gw * gh / fimg / fimg;
        s_cls[tid] = (int)cls;
        s_win[tid] = winner;
    }
    unsigned long long m = __ballot(valid != 0);   // wave 0 holds all GT lanes
    if (tid == 0) s_any = (m != 0ULL);
    __syncthreads();

    // ---------------- main / cls work ---------------------------------------
    int bx = blockIdx.x;
    float loss = 0.0f;
    if (bx < MAIN_BLOCKS) {
        int c = bx * 256 + tid;            // flat cell id == (a<<12)|(y<<6)|x
        int a = c >> 12;
        int y = (c >> 6) & (NG - 1);
        int x = c & (NG - 1);
        int ai = anchor_indices[a];
        float aw = all_anchors[2 * ai], ah = all_anchors[2 * ai + 1];

        const float* rb = raw + ((size_t)(b * (NA * NCH) + a * NCH) << 12)
                              + (y << 6) + x;
        float r0 = rb[0];
        float r1 = rb[1 * 4096];
        float r2 = rb[2 * 4096];
        float r3 = rb[3 * 4096];
        float r4 = rb[4 * 4096];

        float lp = fminf(expf(r0) * aw, fimg);
        float tp = fminf(expf(r1) * ah, fimg);
        float rp = fminf(expf(r2) * aw, fimg);
        float bp = fminf(expf(r3) * ah, fimg);

        float px = ((float)x + 0.5f) * STRIDE_F + (rp - lp) * 0.5f;
        float py = ((float)y + 0.5f) * STRIDE_F + (bp - tp) * 0.5f;
        float pw = lp + rp, ph = tp + bp;
        float base = 0.375f * (pw * ph + 1e-12f);
        float pxl = px - pw * 0.5f, pxr = px + pw * 0.5f;
        float pyt = py - ph * 0.5f, pyb = py + ph * 0.5f;

        // iou >= 0.6  <=>  inter >= 0.375*(areaP + areaG + 1e-12)
        float maxdiff = -1.0f;
        int win = -1;
        #pragma unroll 10
        for (int g = 0; g < NGT; ++g) {
            float4 bb = s_box[g];
            float tlx = fmaxf(pxl, bb.x);
            float tly = fmaxf(pyt, bb.y);
            float brx = fminf(pxr, bb.z);
            float bry = fminf(pyb, bb.w);
            float inter = fmaxf(brx - tlx, 0.0f) * fmaxf(bry - tly, 0.0f);
            maxdiff = fmaxf(maxdiff, inter - (base + s_thr[g]));
            if (s_key[g] == c) win = g;    // ascending g: last match wins
        }

        bool cmask = s_any ? (maxdiff < 0.0f) : true;
        if (win >= 0) {
            loss += bce_logits(r4, 1.0f);  // conf_mask forced true at GT cells
            float4 tl = s_tl[win];
            float w = s_wv[win];
            float d0 = r0 - tl.x, d1 = r1 - tl.y, d2 = r2 - tl.z, d3 = r3 - tl.w;
            loss += 0.5f * w * (d0 * d0 + d1 * d1 + d2 * d2 + d3 * d3);
        } else if (cmask) {
            loss += bce_logits(r4, 0.0f);
        }
    } else {
        // class loss: wave w of this block handles GT g
        int g = (bx - MAIN_BLOCKS) * 4 + (tid >> 6);
        int t = tid & 63;
        if (g < NGT && s_win[g]) {
            int k = s_key[g];
            int bn2 = k >> 12;
            int tj = (k >> 6) & (NG - 1);
            int ti = k & (NG - 1);
            int cc = s_cls[g];
            const float* rc = raw
                + ((size_t)(b * (NA * NCH) + bn2 * NCH + 5) << 12)
                + (tj << 6) + ti;
            float xr = rc[(size_t)t * 4096];
            loss += bce_logits(xr, (t == cc) ? 1.0f : 0.0f);
            if (t < N_CLS - 64) {
                int c2 = t + 64;
                float xr2 = rc[(size_t)c2 * 4096];
                loss += bce_logits(xr2, (c2 == cc) ? 1.0f : 0.0f);
            }
        }
    }

    // ---------------- block reduction + one atomic --------------------------
    for (int off = 32; off > 0; off >>= 1)
        loss += __shfl_down(loss, off, 64);
    if ((tid & 63) == 0) swave[tid >> 6] = loss;
    __syncthreads();
    if (tid == 0)
        atomicAdd(out, swave[0] + swave[1] + swave[2] + swave[3]);
}

extern "C" void kernel_launch(void* const* d_in, const int* in_sizes, int n_in,
                              void* d_out, int out_size, void* d_ws, size_t ws_size,
                              hipStream_t stream) {
    const float* raw            = (const float*)d_in[0];
    const float* labels         = (const float*)d_in[1];
    const float* all_anchors    = (const float*)d_in[2];
    const int*   anchor_indices = (const int*)d_in[3];
    const int*   img_size       = (const int*)d_in[4];
    float* out = (float*)d_out;

    int nB = in_sizes[0] / (NA * NCH * NG * NG);   // 16

    hipMemsetAsync(d_out, 0, sizeof(float), stream);
    fcos_fused<<<dim3(MAIN_BLOCKS + CLS_BLOCKS, nB), 256, 0, stream>>>(
        raw, labels, all_anchors, anchor_indices, img_size, out);
}

// Round 4
// 22.344 us; speedup vs baseline: 3.5024x; 1.1769x over previous
//
#include <hip/hip_runtime.h>
#include <math.h>

#define STRIDE_F 8.0f
#define N_CLS 80
#define NA 3
#define NCH (5 + N_CLS)   // 85
#define NG 64
#define NGT 50
#define NANCH 9
#define EPS_T 1e-8f
#define MAIN_BLOCKS 24            // 24 blocks * 256 thr * 2 cells = NA*NG*NG

__device__ __forceinline__ float bce_logits(float x, float t) {
    return fmaxf(x, 0.0f) - x * t + log1pf(expf(-fabsf(x)));
}

// One fused kernel. grid = (MAIN_BLOCKS, nB). Each thread owns 2 adjacent
// x-cells (float2 loads). Class-loss terms (<=50 GT x 80 classes = 4000) are
// spread flat across the block's threads (tb < 4000 -> one (g,cc) pair each).
__global__ __launch_bounds__(256) void fcos_fused(
        const float* __restrict__ raw,
        const float* __restrict__ labels,
        const float* __restrict__ all_anchors,
        const int* __restrict__ anchor_indices,
        const int* __restrict__ img_size,
        float* __restrict__ out) {
    __shared__ float4 s_box[NGT];   // corner box (xl,yt,xr,yb)
    __shared__ float4 s_tl[NGT];    // target ltrb logs
    __shared__ float2 s_tk[NGT];    // (0.375*areaG, key-as-float-bits)
    __shared__ int    s_key[NGT];   // valid ? (bn<<12)|(tj<<6)|ti : -1
    __shared__ float  s_wv[NGT];    // wvec
    __shared__ int    s_cls[NGT];
    __shared__ int    s_win[NGT];   // winner && valid
    __shared__ int    s_any;
    __shared__ float  swave[4];

    int b = blockIdx.y;
    int tid = threadIdx.x;
    float fimg = (float)(*img_size);

    // ---------------- per-block GT prep (threads 0..49, wave 0) -------------
    int valid = 0, key = -1, bn = 0;
    float gx = 0, gy = 0, gw = 0, gh = 0, cls = 0;
    if (tid < NGT) {
        const float* lab = labels + (b * NGT + tid) * 5;
        cls = lab[0];
        gx = lab[1]; gy = lab[2]; gw = lab[3]; gh = lab[4];
        int best = 0; float bi = -1.0f;
        for (int k = 0; k < NANCH; ++k) {
            float aw = all_anchors[2 * k], ah = all_anchors[2 * k + 1];
            float inter = fminf(gw, aw) * fminf(gh, ah);
            float iou = inter / (gw * gh + aw * ah - inter);
            if (iou > bi) { bi = iou; best = k; }
        }
        bn = best % NA;
        for (int j = 0; j < NA; ++j) if (anchor_indices[j] == best) valid = 1;
        int ti = (int)(gx / STRIDE_F);
        int tj = (int)(gy / STRIDE_F);
        key = valid ? ((bn << 12) | (tj << 6) | ti) : -1;
        s_key[tid] = key;
    }
    __syncthreads();
    if (tid < NGT) {
        // JAX scatter "last valid update wins"
        int winner = valid;
        for (int gp = tid + 1; gp < NGT; ++gp)
            if (s_key[gp] == key) winner = 0;

        int ai = anchor_indices[bn];
        float aw = all_anchors[2 * ai], ah = all_anchors[2 * ai + 1];
        float ccx = (floorf(gx / STRIDE_F) + 0.5f) * STRIDE_F;
        float ccy = (floorf(gy / STRIDE_F) + 0.5f) * STRIDE_F;
        float l   = fmaxf(ccx - (gx - gw * 0.5f), 0.0f);
        float t   = fmaxf(ccy - (gy - gh * 0.5f), 0.0f);
        float r   = fmaxf(gx + gw * 0.5f - ccx, 0.0f);
        float btm = fmaxf(gy + gh * 0.5f - ccy, 0.0f);

        s_box[tid] = make_float4(gx - gw * 0.5f, gy - gh * 0.5f,
                                 gx + gw * 0.5f, gy + gh * 0.5f);
        s_tk[tid]  = make_float2(0.375f * (gw * gh), __int_as_float(key));
        s_tl[tid]  = make_float4(logf(l / aw + EPS_T), logf(t / ah + EPS_T),
                                 logf(r / aw + EPS_T), logf(btm / ah + EPS_T));
        s_wv[tid]  = 2.0f - gw * gh / fimg / fimg;
        s_cls[tid] = (int)cls;
        s_win[tid] = winner;
    }
    unsigned long long m = __ballot(valid != 0);   // wave 0 holds all GT lanes
    if (tid == 0) s_any = (m != 0ULL);
    __syncthreads();

    // ---------------- main: 2 cells per thread ------------------------------
    int cp = (blockIdx.x * 256 + tid) * 2;   // flat cell id, even
    int a = cp >> 12;
    int y = (cp >> 6) & (NG - 1);
    int x0 = cp & (NG - 1);
    int ai = anchor_indices[a];
    float aw = all_anchors[2 * ai], ah = all_anchors[2 * ai + 1];

    const float* rb = raw + ((size_t)(b * (NA * NCH) + a * NCH) << 12)
                          + (y << 6) + x0;
    float2 r0 = *(const float2*)(rb);
    float2 r1 = *(const float2*)(rb + 1 * 4096);
    float2 r2 = *(const float2*)(rb + 2 * 4096);
    float2 r3 = *(const float2*)(rb + 3 * 4096);
    float2 r4 = *(const float2*)(rb + 4 * 4096);

    float pxl[2], pxr[2], pyt[2], pyb[2], basev[2];
    {
        float cy = ((float)y + 0.5f) * STRIDE_F;
        float e0, e1, e2, e3, lp, tp, rp, bp, px, py, pw, ph, cx;
        // cell 0
        e0 = r0.x; e1 = r1.x; e2 = r2.x; e3 = r3.x;
        lp = fminf(expf(e0) * aw, fimg);
        tp = fminf(expf(e1) * ah, fimg);
        rp = fminf(expf(e2) * aw, fimg);
        bp = fminf(expf(e3) * ah, fimg);
        cx = ((float)x0 + 0.5f) * STRIDE_F;
        px = cx + (rp - lp) * 0.5f;
        py = cy + (bp - tp) * 0.5f;
        pw = lp + rp; ph = tp + bp;
        basev[0] = 0.375f * (pw * ph + 1e-12f);
        pxl[0] = px - pw * 0.5f; pxr[0] = px + pw * 0.5f;
        pyt[0] = py - ph * 0.5f; pyb[0] = py + ph * 0.5f;
        // cell 1
        e0 = r0.y; e1 = r1.y; e2 = r2.y; e3 = r3.y;
        lp = fminf(expf(e0) * aw, fimg);
        tp = fminf(expf(e1) * ah, fimg);
        rp = fminf(expf(e2) * aw, fimg);
        bp = fminf(expf(e3) * ah, fimg);
        cx = ((float)x0 + 1.5f) * STRIDE_F;
        px = cx + (rp - lp) * 0.5f;
        py = cy + (bp - tp) * 0.5f;
        pw = lp + rp; ph = tp + bp;
        basev[1] = 0.375f * (pw * ph + 1e-12f);
        pxl[1] = px - pw * 0.5f; pxr[1] = px + pw * 0.5f;
        pyt[1] = py - ph * 0.5f; pyb[1] = py + ph * 0.5f;
    }

    // iou >= 0.6  <=>  inter >= 0.375*(areaP + areaG + 1e-12)
    float maxd0 = -1.0f, maxd1 = -1.0f;
    int win0 = -1, win1 = -1;
    #pragma unroll 10
    for (int g = 0; g < NGT; ++g) {
        float4 bb = s_box[g];
        float2 tk = s_tk[g];
        {
            float tlx = fmaxf(pxl[0], bb.x);
            float tly = fmaxf(pyt[0], bb.y);
            float brx = fminf(pxr[0], bb.z);
            float bry = fminf(pyb[0], bb.w);
            float inter = fmaxf(brx - tlx, 0.0f) * fmaxf(bry - tly, 0.0f);
            maxd0 = fmaxf(maxd0, inter - (basev[0] + tk.x));
        }
        {
            float tlx = fmaxf(pxl[1], bb.x);
            float tly = fmaxf(pyt[1], bb.y);
            float brx = fminf(pxr[1], bb.z);
            float bry = fminf(pyb[1], bb.w);
            float inter = fmaxf(brx - tlx, 0.0f) * fmaxf(bry - tly, 0.0f);
            maxd1 = fmaxf(maxd1, inter - (basev[1] + tk.x));
        }
        int kk = __float_as_int(tk.y);
        if (kk == cp)     win0 = g;   // ascending g: last match wins
        if (kk == cp + 1) win1 = g;
    }

    float loss = 0.0f;
    bool anyv = (s_any != 0);
    // cell 0
    if (win0 >= 0) {
        loss += bce_logits(r4.x, 1.0f);
        float4 tl = s_tl[win0];
        float w = s_wv[win0];
        float d0 = r0.x - tl.x, d1 = r1.x - tl.y, d2 = r2.x - tl.z, d3 = r3.x - tl.w;
        loss += 0.5f * w * (d0 * d0 + d1 * d1 + d2 * d2 + d3 * d3);
    } else if (!anyv || maxd0 < 0.0f) {
        loss += bce_logits(r4.x, 0.0f);
    }
    // cell 1
    if (win1 >= 0) {
        loss += bce_logits(r4.y, 1.0f);
        float4 tl = s_tl[win1];
        float w = s_wv[win1];
        float d0 = r0.y - tl.x, d1 = r1.y - tl.y, d2 = r2.y - tl.z, d3 = r3.y - tl.w;
        loss += 0.5f * w * (d0 * d0 + d1 * d1 + d2 * d2 + d3 * d3);
    } else if (!anyv || maxd1 < 0.0f) {
        loss += bce_logits(r4.y, 0.0f);
    }

    // ---------------- class loss, spread flat over threads ------------------
    int tb = blockIdx.x * 256 + tid;         // [0, 6144)
    if (tb < NGT * N_CLS) {
        int g = tb / N_CLS;                  // const-div -> magic mul
        int cc = tb - g * N_CLS;
        if (s_win[g]) {
            int k = s_key[g];
            int bn2 = k >> 12;
            int tj = (k >> 6) & (NG - 1);
            int ti = k & (NG - 1);
            const float* rc = raw
                + ((size_t)(b * (NA * NCH) + bn2 * NCH + 5 + cc) << 12)
                + (tj << 6) + ti;
            loss += bce_logits(*rc, (cc == s_cls[g]) ? 1.0f : 0.0f);
        }
    }

    // ---------------- block reduction + one atomic --------------------------
    for (int off = 32; off > 0; off >>= 1)
        loss += __shfl_down(loss, off, 64);
    if ((tid & 63) == 0) swave[tid >> 6] = loss;
    __syncthreads();
    if (tid == 0)
        atomicAdd(out, swave[0] + swave[1] + swave[2] + swave[3]);
}

extern "C" void kernel_launch(void* const* d_in, const int* in_sizes, int n_in,
                              void* d_out, int out_size, void* d_ws, size_t ws_size,
                              hipStream_t stream) {
    const float* raw            = (const float*)d_in[0];
    const float* labels         = (const float*)d_in[1];
    const float* all_anchors    = (const float*)d_in[2];
    const int*   anchor_indices = (const int*)d_in[3];
    const int*   img_size       = (const int*)d_in[4];
    float* out = (float*)d_out;

    int nB = in_sizes[0] / (NA * NCH * NG * NG);   // 16

    hipMemsetAsync(d_out, 0, sizeof(float), stream);
    fcos_fused<<<dim3(MAIN_BLOCKS, nB), 256, 0, stream>>>(
        raw, labels, all_anchors, anchor_indices, img_size, out);
}